// Round 31
// baseline (143.226 us; speedup 1.0000x reference)
//
#include <hip/hip_runtime.h>
#include <math.h>

typedef _Float16 f16;
typedef _Float16 f16x8 __attribute__((ext_vector_type(8)));
typedef _Float16 f16x4 __attribute__((ext_vector_type(4)));
typedef float f32x4 __attribute__((ext_vector_type(4)));

static __device__ inline f32x4 mfma16(f16x8 a, f16x8 b, f32x4 c) {
    return __builtin_amdgcn_mfma_f32_16x16x32_f16(a, b, c, 0, 0, 0);
}

static __device__ inline void gload16(const void* g, void* l) {
    __builtin_amdgcn_global_load_lds(
        (const __attribute__((address_space(1))) void*)g,
        (__attribute__((address_space(3))) void*)l, 16, 0, 0);
}

// Stage a [128 rows][64 f16] tile (row-stride 1024) into linear LDS,
// inverse-XOR on the global source chunk: LDS[row][ch] = G[row][ch^(row&7)].
static __device__ inline void stage128x64(const f16* __restrict__ g, f16* lds, int tid) {
#pragma unroll
    for (int i = 0; i < 4; i++) {
        const int c = tid + i * 256;
        const int row = c >> 3, ch = c & 7;
        gload16(g + (size_t)row * 1024 + ((ch ^ (row & 7)) * 8),
                lds + (size_t)(c & ~63) * 8);      // wave-uniform base; HW adds lane*16B
    }
}

// Stage a [64 rows][64 f16] tile (arbitrary row stride) with 256 threads, same swizzle.
static __device__ inline void stage64x64(const f16* __restrict__ g, size_t rstride,
                                         f16* lds, int tid) {
#pragma unroll
    for (int r = 0; r < 2; r++) {
        const int c = tid + r * 256;
        const int row = c >> 3, ch = c & 7;
        gload16(g + (size_t)row * rstride + ((ch ^ (row & 7)) * 8),
                lds + (size_t)(c & ~63) * 8);
    }
}

// ---------------- Kernel 1: convert weights + activations f32->f16, AND mask flag scan ----------------
// idx < 4194304: conversion sweep. idx >= 4194304: scan mask float4s, set flag (at d_out[0]).
__global__ __launch_bounds__(256) void prep_all(const float* __restrict__ wqkv,
                                                const float* __restrict__ wo,
                                                const float* __restrict__ query,
                                                const float* __restrict__ key,
                                                const float* __restrict__ value,
                                                const float* __restrict__ mask,
                                                f16* __restrict__ dst,
                                                unsigned* __restrict__ flag) {
    int idx = blockIdx.x * 256 + threadIdx.x;   // 5242880 total
    if (idx < 4194304) {
        const float* src;
        if      (idx <  786432) src = wqkv  + (size_t)idx * 4;
        else if (idx < 1048576) src = wo    + (size_t)(idx -  786432) * 4;
        else if (idx < 2097152) src = query + (size_t)(idx - 1048576) * 4;
        else if (idx < 3145728) src = key   + (size_t)(idx - 2097152) * 4;
        else                    src = value + (size_t)(idx - 3145728) * 4;
        const float4 v = *(const float4*)src;
        f16x4 h = { (f16)v.x, (f16)v.y, (f16)v.z, (f16)v.w };
        *(f16x4*)(dst + (size_t)idx * 4) = h;
    } else {
        const int midx = idx - 4194304;         // 0..1048575
        const float4 v = *(const float4*)(mask + (size_t)midx * 4);
        const int nz = (v.x != 0.f) | (v.y != 0.f) | (v.z != 0.f) | (v.w != 0.f);
        if (__any(nz) && (threadIdx.x & 63) == 0) atomicOr(flag, 1u);
    }
}

// ---------------- Kernel 2: QKV GEMM; V-segment writes Vt DIRECTLY (vtrans fused) ----------------
__global__ __launch_bounds__(256) void qkv_gemm_v6(const f16* __restrict__ Acts,
                                                   const f16* __restrict__ Wqkv,
                                                   const float* __restrict__ bias,
                                                   f16* __restrict__ Qb,
                                                   f16* __restrict__ Kb,
                                                   f16* __restrict__ Vt) {
    __shared__ __align__(16) f16 As[2][128 * 64];
    __shared__ __align__(16) f16 Bs[2][128 * 64];
    __shared__ float invfS[512];
    const int tid = threadIdx.x;
    const int m0 = blockIdx.x * 128;
    const int n0 = blockIdx.y * 128;
    const int seg = n0 >> 10;                       // 0=q 1=k 2=v
    const f16* __restrict__ A = Acts + (size_t)seg * 4194304 + (size_t)m0 * 1024;
    const f16* __restrict__ B = Wqkv + (size_t)n0 * 1024;
    const int wid = tid >> 6, lane = tid & 63;
    const int wr = wid >> 1, wc = wid & 1;
    const int lr = lane & 15, lg = lane >> 4;
    const int sw = lr & 7;

    // inv_freq[i] = 10000^(-i/512) in f64 (matches f32-exact table to ~1ulp)
    {
        const double C = -0.025952563241307517;     // -log2(10000)/512
        invfS[tid]       = (float)exp2((double)tid * C);
        invfS[tid + 256] = (float)exp2((double)(tid + 256) * C);
    }

    f32x4 acc[4][4] = {};

    stage128x64(A, As[0], tid);                     // tile 0 in flight
    stage128x64(B, Bs[0], tid);

    for (int t = 0; t < 16; ++t) {
        const int cur = t & 1;
        if (t < 15) {
            stage128x64(A + (t + 1) * 64, As[cur ^ 1], tid);
            stage128x64(B + (t + 1) * 64, Bs[cur ^ 1], tid);
            asm volatile("s_waitcnt vmcnt(8)" ::: "memory");
        } else {
            asm volatile("s_waitcnt vmcnt(0)" ::: "memory");
        }
        __builtin_amdgcn_s_barrier();
        __builtin_amdgcn_sched_barrier(0);
#pragma unroll
        for (int kk = 0; kk < 2; kk++) {
            f16x8 a[4], b[4];
#pragma unroll
            for (int i = 0; i < 4; i++)
                a[i] = *(const f16x8*)&As[cur][(wr * 64 + i * 16 + lr) * 64 + (((kk << 2) + lg) ^ sw) * 8];
#pragma unroll
            for (int j = 0; j < 4; j++)
                b[j] = *(const f16x8*)&Bs[cur][(wc * 64 + j * 16 + lr) * 64 + (((kk << 2) + lg) ^ sw) * 8];
#pragma unroll
            for (int i = 0; i < 4; i++)
#pragma unroll
                for (int j = 0; j < 4; j++) acc[i][j] = mfma16(a[i], b[j], acc[i][j]);
        }
        __builtin_amdgcn_s_barrier();
    }

    if (seg == 2) {
        // -------- V path: transpose through dead As/Bs LDS, write Vt [bh][d][t] --------
        __syncthreads();                            // full fence: K-loop LDS reads done
        f16 (*T0)[136] = (f16(*)[136])&As[0][0];    // e_local 0..63
        f16 (*T1)[136] = (f16(*)[136])&Bs[0][0];    // e_local 64..127
#pragma unroll
        for (int j = 0; j < 4; j++) {
            const int el = wc * 64 + j * 16 + lr;   // 0..127
            const float bv = bias[n0 + el];
            f16 (*T)[136] = (wc == 0) ? T0 : T1;    // wave-uniform
#pragma unroll
            for (int i = 0; i < 4; i++)
#pragma unroll
                for (int r = 0; r < 4; r++) {
                    const int ml = wr * 64 + i * 16 + lg * 4 + r;   // 0..127
                    T[el & 63][ml] = (f16)(acc[i][j][r] + bv);
                }
        }
        __syncthreads();
        // write phase: thread c -> (e_local = c&127, bb = c>>7); 64 t contiguous
        const int el2 = tid & 127, bb2 = tid >> 7;
        const f16* row = (el2 < 64) ? T0[el2] : T1[el2 - 64];       // wave-uniform select
        const int e2 = (n0 & 1023) + el2;
        f16* dst = Vt + (((size_t)(bb2 * 16 + (e2 >> 6))) * 64 + (e2 & 63)) * 2048 + (m0 >> 1);
#pragma unroll
        for (int g = 0; g < 8; g++) {
            f16x8 v;
#pragma unroll
            for (int u = 0; u < 8; u++) v[u] = row[(g * 8 + u) * 2 + bb2];
            *(f16x8*)(dst + g * 8) = v;
        }
        return;
    }

    // -------- Q/K path: unchanged proven epilogue (bias + scale + rotary) --------
    f16* __restrict__ Out = (seg == 0) ? Qb : Kb;
#pragma unroll
    for (int i = 0; i < 4; i++) {
#pragma unroll
        for (int j = 0; j < 4; j++) {
            const int n = n0 + wc * 64 + j * 16 + lr;
            const int e = n & 1023;
            const int h = e >> 6, d = e & 63;
            const float bv = bias[n];
            const float invf = invfS[e >> 1];
#pragma unroll
            for (int r = 0; r < 4; r++) {
                const int m = m0 + wr * 64 + i * 16 + lg * 4 + r;
                const int t = m >> 1, bb = m & 1;
                float val = acc[i][j][r] + bv;
                if (seg == 0) val *= 0.125f;        // Dh^-0.5
                {                                    // rotary (q and k)
                    const float vp = __shfl_xor(val, 1);
                    float sn, cn;
                    __sincosf((float)t * invf, &sn, &cn);
                    val = (e & 1) ? fmaf(vp, sn, val * cn) : fmaf(-vp, sn, val * cn);
                }
                Out[((size_t)(bb * 16 + h) * 2048 + t) * 64 + d] = (f16)val;
            }
        }
    }
}

// ---------------- Kernel 4: flash attention, TRIPLE-buffered K/V, ONE barrier/iter ----------------
__global__ __launch_bounds__(512) void attn(const f16* __restrict__ Qb,
                                            const f16* __restrict__ Kb,
                                            const f16* __restrict__ Vt,
                                            const float* __restrict__ mask,
                                            const unsigned* __restrict__ flag,
                                            f16* __restrict__ AO) {
    __shared__ __align__(16) f16 Ks[3][64 * 64];
    __shared__ __align__(16) f16 Vs[3][64 * 64];
    __shared__ __align__(16) f16 Pl[8][16][72];
    const int bh = blockIdx.x;
    const int b = bh >> 4, h = bh & 15;
    const int tid = threadIdx.x, wid = tid >> 6, lane = tid & 63;
    const int lr = lane & 15, lg = lane >> 4;
    const int l0 = blockIdx.y * 128 + wid * 16;
    const bool use_mask = (*flag) != 0;             // wave-uniform

    const int srow = tid >> 3;
    const int sc16 = (tid & 7) ^ (srow & 7);
    const f16* Kgs = Kb + ((size_t)bh * 2048 + srow) * 64 + sc16 * 8;
    const f16* Vgs = Vt + ((size_t)bh * 64 + srow) * 2048 + sc16 * 8;

    const f16* __restrict__ Qp = Qb + ((size_t)bh * 2048 + l0) * 64;
    f16x8 aq[2];
    aq[0] = *(const f16x8*)(Qp + lr * 64 + lg * 8);
    aq[1] = *(const f16x8*)(Qp + lr * 64 + 32 + lg * 8);

    float l_run[4] = {0.f, 0.f, 0.f, 0.f};
    f32x4 acc_o[4] = {};

    // prologue: tile 0 in flight
    gload16(Kgs, &Ks[0][wid * 512]);
    gload16(Vgs, &Vs[0][wid * 512]);

    int cur = 0;
    for (int t = 0; t < 32; ++t) {
        const int nxt = (cur == 2) ? 0 : cur + 1;
        if (t < 31) {                               // prefetch tile t+1 into 3rd buffer
            gload16(Kgs + (size_t)(t + 1) * 4096, &Ks[nxt][wid * 512]);
            gload16(Vgs + (size_t)(t + 1) * 64,   &Vs[nxt][wid * 512]);
            asm volatile("s_waitcnt vmcnt(2)" ::: "memory");   // tile t landed; t+1 in flight
        } else {
            asm volatile("s_waitcnt vmcnt(0)" ::: "memory");
        }
        __builtin_amdgcn_s_barrier();               // single barrier per iteration
        __builtin_amdgcn_sched_barrier(0);          // pin all following ops below the barrier

        float mk[4][4];
        if (use_mask) {
#pragma unroll
            for (int js = 0; js < 4; js++)
#pragma unroll
                for (int r = 0; r < 4; r++)
                    mk[js][r] = mask[(size_t)(l0 + lg * 4 + r) * 2048 + t * 64 + js * 16 + lr];
        }

        f32x4 sc[4] = {};
#pragma unroll
        for (int js = 0; js < 4; js++) {
            const int row = js * 16 + lr;
#pragma unroll
            for (int kk = 0; kk < 2; kk++) {
                const f16x8 bk = *(const f16x8*)&Ks[cur][row * 64 + ((kk * 4 + lg) ^ (row & 7)) * 8];
                sc[js] = mfma16(aq[kk], bk, sc[js]);
            }
        }

        if (use_mask) {
#pragma unroll
            for (int js = 0; js < 4; js++)
#pragma unroll
                for (int r = 0; r < 4; r++) {
                    const float p = __expf(sc[js][r] + mk[js][r] - 4.0f);
                    l_run[r] += p;
                    Pl[wid][lg * 4 + r][js * 16 + lr] = (f16)p;
                }
        } else {
#pragma unroll
            for (int js = 0; js < 4; js++)
#pragma unroll
                for (int r = 0; r < 4; r++) {
                    const float p = __expf(sc[js][r] - 4.0f);
                    l_run[r] += p;
                    Pl[wid][lg * 4 + r][js * 16 + lr] = (f16)p;
                }
        }

        f16x8 pa[2];
#pragma unroll
        for (int kk = 0; kk < 2; kk++) pa[kk] = *(const f16x8*)&Pl[wid][lr][kk * 32 + lg * 8];
#pragma unroll
        for (int j = 0; j < 4; j++) {
            const int row = j * 16 + lr;
#pragma unroll
            for (int kk = 0; kk < 2; kk++) {
                const f16x8 bv = *(const f16x8*)&Vs[cur][row * 64 + ((kk * 4 + lg) ^ (row & 7)) * 8];
                acc_o[j] = mfma16(pa[kk], bv, acc_o[j]);
            }
        }
        cur = nxt;                                  // no end barrier: 3-buffer rotation is safe
    }

#pragma unroll
    for (int r = 0; r < 4; r++)
#pragma unroll
        for (int off = 1; off < 16; off <<= 1) l_run[r] += __shfl_xor(l_run[r], off);

#pragma unroll
    for (int j = 0; j < 4; j++)
#pragma unroll
        for (int r = 0; r < 4; r++) {
            const float o = acc_o[j][r] / l_run[r];
            const int l = l0 + lg * 4 + r;
            AO[((size_t)l * 2 + b) * 1024 + h * 64 + j * 16 + lr] = (f16)o;
        }
}

// ---------------- Kernel 5: out projection GEMM, TRIPLE-buffered, ONE barrier/iter ----------------
__global__ __launch_bounds__(256) void oproj_gemm_v5(const f16* __restrict__ AO,
                                                     const f16* __restrict__ Wo,
                                                     const float* __restrict__ bias,
                                                     float* __restrict__ out) {
    __shared__ __align__(16) f16 As[3][64 * 64];
    __shared__ __align__(16) f16 Bs[3][128 * 64];
    const int tid = threadIdx.x;
    const int m0 = blockIdx.x * 64;
    const int n0 = blockIdx.y * 128;
    const int wid = tid >> 6, lane = tid & 63;
    const int wr = wid >> 1, wc = wid & 1;          // 2x2 waves over 64x128
    const int lr = lane & 15, lg = lane >> 4;
    const int sw = lr & 7;
    const f16* __restrict__ A = AO + (size_t)m0 * 1024;
    const f16* __restrict__ B = Wo + (size_t)n0 * 1024;

    f32x4 acc[2][4] = {};

    stage64x64(A, 1024, As[0], tid);                // 2 loads
    stage128x64(B, Bs[0], tid);                     // 4 loads

    int cur = 0;
    for (int t = 0; t < 16; ++t) {
        const int nxt = (cur == 2) ? 0 : cur + 1;
        if (t < 15) {
            stage64x64(A + (t + 1) * 64, 1024, As[nxt], tid);
            stage128x64(B + (t + 1) * 64, Bs[nxt], tid);
            asm volatile("s_waitcnt vmcnt(6)" ::: "memory");   // tile t's 6 loads done
        } else {
            asm volatile("s_waitcnt vmcnt(0)" ::: "memory");
        }
        __builtin_amdgcn_s_barrier();               // single barrier per iteration
        __builtin_amdgcn_sched_barrier(0);
#pragma unroll
        for (int kk = 0; kk < 2; kk++) {
            f16x8 a[2], b[4];
#pragma unroll
            for (int i = 0; i < 2; i++)
                a[i] = *(const f16x8*)&As[cur][(wr * 32 + i * 16 + lr) * 64 + (((kk << 2) + lg) ^ sw) * 8];
#pragma unroll
            for (int j = 0; j < 4; j++)
                b[j] = *(const f16x8*)&Bs[cur][(wc * 64 + j * 16 + lr) * 64 + (((kk << 2) + lg) ^ sw) * 8];
#pragma unroll
            for (int i = 0; i < 2; i++)
#pragma unroll
                for (int j = 0; j < 4; j++) acc[i][j] = mfma16(a[i], b[j], acc[i][j]);
        }
        cur = nxt;                                  // no end barrier: 3-buffer rotation
    }

#pragma unroll
    for (int i = 0; i < 2; i++)
#pragma unroll
        for (int j = 0; j < 4; j++) {
            const int n = n0 + wc * 64 + j * 16 + lr;
            const float bv = bias[n];
#pragma unroll
            for (int r = 0; r < 4; r++) {
                const int m = m0 + wr * 32 + i * 16 + lg * 4 + r;
                out[(size_t)m * 1024 + n] = acc[i][j][r] + bv;
            }
        }
}

extern "C" void kernel_launch(void* const* d_in, const int* in_sizes, int n_in,
                              void* d_out, int out_size, void* d_ws, size_t ws_size,
                              hipStream_t stream) {
    const float* query  = (const float*)d_in[0];
    const float* key    = (const float*)d_in[1];
    const float* value  = (const float*)d_in[2];
    const float* amask  = (const float*)d_in[5];
    const float* w_in   = (const float*)d_in[6];
    const float* b_in   = (const float*)d_in[7];
    const float* w_out  = (const float*)d_in[8];
    const float* b_out  = (const float*)d_in[9];
    float* out = (float*)d_out;

    f16* ws    = (f16*)d_ws;
    f16* Wqkv  = ws;                        // 3145728
    f16* Wo    = ws + 3145728;              // 1048576
    f16* Acts  = ws + 4194304;              // 3*4194304 (Aq|Ak|Av)
    f16* Qb    = ws + 16777216;
    f16* Kb    = ws + 20971520;
    f16* Vt    = ws + 25165824;             // V written transposed directly by qkv
    f16* AO    = ws + 8388608;              // reuse Ak (dead after qkv)
    unsigned* flag = (unsigned*)d_out;      // d_out untouched until oproj; consumed by attn first

    hipMemsetAsync(flag, 0, 4, stream);
    prep_all<<<20480, 256, 0, stream>>>(w_in, w_out, query, key, value, amask, ws, flag);
    qkv_gemm_v6<<<dim3(32, 24), 256, 0, stream>>>(Acts, Wqkv, b_in, Qb, Kb, Vt);
    attn<<<dim3(32, 16), 512, 0, stream>>>(Qb, Kb, Vt, amask, flag, AO);
    oproj_gemm_v5<<<dim3(64, 8), 256, 0, stream>>>(AO, Wo, b_out, out);
}

// Round 32
// 139.139 us; speedup vs baseline: 1.0294x; 1.0294x over previous
//
#include <hip/hip_runtime.h>
#include <math.h>

typedef _Float16 f16;
typedef _Float16 f16x8 __attribute__((ext_vector_type(8)));
typedef _Float16 f16x4 __attribute__((ext_vector_type(4)));
typedef float f32x4 __attribute__((ext_vector_type(4)));

static __device__ inline f32x4 mfma16(f16x8 a, f16x8 b, f32x4 c) {
    return __builtin_amdgcn_mfma_f32_16x16x32_f16(a, b, c, 0, 0, 0);
}

static __device__ inline void gload16(const void* g, void* l) {
    __builtin_amdgcn_global_load_lds(
        (const __attribute__((address_space(1))) void*)g,
        (__attribute__((address_space(3))) void*)l, 16, 0, 0);
}

// Stage a [128 rows][64 f16] tile (row-stride 1024) into linear LDS,
// inverse-XOR on the global source chunk: LDS[row][ch] = G[row][ch^(row&7)].
static __device__ inline void stage128x64(const f16* __restrict__ g, f16* lds, int tid) {
#pragma unroll
    for (int i = 0; i < 4; i++) {
        const int c = tid + i * 256;
        const int row = c >> 3, ch = c & 7;
        gload16(g + (size_t)row * 1024 + ((ch ^ (row & 7)) * 8),
                lds + (size_t)(c & ~63) * 8);      // wave-uniform base; HW adds lane*16B
    }
}

// Stage a [64 rows][64 f16] tile (arbitrary row stride) with 256 threads, same swizzle.
static __device__ inline void stage64x64(const f16* __restrict__ g, size_t rstride,
                                         f16* lds, int tid) {
#pragma unroll
    for (int r = 0; r < 2; r++) {
        const int c = tid + r * 256;
        const int row = c >> 3, ch = c & 7;
        gload16(g + (size_t)row * rstride + ((ch ^ (row & 7)) * 8),
                lds + (size_t)(c & ~63) * 8);
    }
}

// ---------------- Kernel 1: convert weights + activations f32 -> f16 ----------------
__global__ __launch_bounds__(256) void prep_all(const float* __restrict__ wqkv,
                                                const float* __restrict__ wo,
                                                const float* __restrict__ query,
                                                const float* __restrict__ key,
                                                const float* __restrict__ value,
                                                f16* __restrict__ dst) {
    int idx = blockIdx.x * 256 + threadIdx.x;   // 4194304 float4s
    const float* src;
    if      (idx <  786432) src = wqkv  + (size_t)idx * 4;
    else if (idx < 1048576) src = wo    + (size_t)(idx -  786432) * 4;
    else if (idx < 2097152) src = query + (size_t)(idx - 1048576) * 4;
    else if (idx < 3145728) src = key   + (size_t)(idx - 2097152) * 4;
    else                    src = value + (size_t)(idx - 3145728) * 4;
    const float4 v = *(const float4*)src;
    f16x4 h = { (f16)v.x, (f16)v.y, (f16)v.z, (f16)v.w };
    *(f16x4*)(dst + (size_t)idx * 4) = h;
}

// ---------------- Kernel 1b: mask "any nonzero" flag (no conversion) ----------------
__global__ __launch_bounds__(256) void mask_flag(const float* __restrict__ m,
                                                 unsigned* __restrict__ flag) {
    int idx = blockIdx.x * 256 + threadIdx.x;   // 1048576 float4s
    const float4 v = *(const float4*)(m + (size_t)idx * 4);
    const int nz = (v.x != 0.f) | (v.y != 0.f) | (v.z != 0.f) | (v.w != 0.f);
    if (__any(nz) && (threadIdx.x & 63) == 0) atomicOr(flag, 1u);
}

// ---------------- Kernel 2: QKV GEMM; V-segment writes Vt DIRECTLY (vtrans fused) ----------------
__global__ __launch_bounds__(256) void qkv_gemm_v6(const f16* __restrict__ Acts,
                                                   const f16* __restrict__ Wqkv,
                                                   const float* __restrict__ bias,
                                                   f16* __restrict__ Qb,
                                                   f16* __restrict__ Kb,
                                                   f16* __restrict__ Vt) {
    __shared__ __align__(16) f16 As[2][128 * 64];
    __shared__ __align__(16) f16 Bs[2][128 * 64];
    __shared__ float invfS[512];
    const int tid = threadIdx.x;
    const int m0 = blockIdx.x * 128;
    const int n0 = blockIdx.y * 128;
    const int seg = n0 >> 10;                       // 0=q 1=k 2=v
    const f16* __restrict__ A = Acts + (size_t)seg * 4194304 + (size_t)m0 * 1024;
    const f16* __restrict__ B = Wqkv + (size_t)n0 * 1024;
    const int wid = tid >> 6, lane = tid & 63;
    const int wr = wid >> 1, wc = wid & 1;
    const int lr = lane & 15, lg = lane >> 4;
    const int sw = lr & 7;

    // inv_freq[i] = 10000^(-i/512) in f64 (matches f32-exact table to ~1ulp)
    {
        const double C = -0.025952563241307517;     // -log2(10000)/512
        invfS[tid]       = (float)exp2((double)tid * C);
        invfS[tid + 256] = (float)exp2((double)(tid + 256) * C);
    }

    f32x4 acc[4][4] = {};

    stage128x64(A, As[0], tid);                     // tile 0 in flight
    stage128x64(B, Bs[0], tid);

    for (int t = 0; t < 16; ++t) {
        const int cur = t & 1;
        if (t < 15) {
            stage128x64(A + (t + 1) * 64, As[cur ^ 1], tid);
            stage128x64(B + (t + 1) * 64, Bs[cur ^ 1], tid);
            asm volatile("s_waitcnt vmcnt(8)" ::: "memory");
        } else {
            asm volatile("s_waitcnt vmcnt(0)" ::: "memory");
        }
        __builtin_amdgcn_s_barrier();
        __builtin_amdgcn_sched_barrier(0);
#pragma unroll
        for (int kk = 0; kk < 2; kk++) {
            f16x8 a[4], b[4];
#pragma unroll
            for (int i = 0; i < 4; i++)
                a[i] = *(const f16x8*)&As[cur][(wr * 64 + i * 16 + lr) * 64 + (((kk << 2) + lg) ^ sw) * 8];
#pragma unroll
            for (int j = 0; j < 4; j++)
                b[j] = *(const f16x8*)&Bs[cur][(wc * 64 + j * 16 + lr) * 64 + (((kk << 2) + lg) ^ sw) * 8];
#pragma unroll
            for (int i = 0; i < 4; i++)
#pragma unroll
                for (int j = 0; j < 4; j++) acc[i][j] = mfma16(a[i], b[j], acc[i][j]);
        }
        __builtin_amdgcn_s_barrier();
    }

    if (seg == 2) {
        // -------- V path: transpose through dead As/Bs LDS, write Vt [bh][d][t] --------
        __syncthreads();                            // full fence: K-loop LDS reads done
        f16 (*T0)[136] = (f16(*)[136])&As[0][0];    // e_local 0..63
        f16 (*T1)[136] = (f16(*)[136])&Bs[0][0];    // e_local 64..127
#pragma unroll
        for (int j = 0; j < 4; j++) {
            const int el = wc * 64 + j * 16 + lr;   // 0..127
            const float bv = bias[n0 + el];
            f16 (*T)[136] = (wc == 0) ? T0 : T1;    // wave-uniform
#pragma unroll
            for (int i = 0; i < 4; i++)
#pragma unroll
                for (int r = 0; r < 4; r++) {
                    const int ml = wr * 64 + i * 16 + lg * 4 + r;   // 0..127
                    T[el & 63][ml] = (f16)(acc[i][j][r] + bv);
                }
        }
        __syncthreads();
        // write phase: thread c -> (e_local = c&127, bb = c>>7); 64 t contiguous
        const int el2 = tid & 127, bb2 = tid >> 7;
        const f16* row = (el2 < 64) ? T0[el2] : T1[el2 - 64];       // wave-uniform select
        const int e2 = (n0 & 1023) + el2;
        f16* dst = Vt + (((size_t)(bb2 * 16 + (e2 >> 6))) * 64 + (e2 & 63)) * 2048 + (m0 >> 1);
#pragma unroll
        for (int g = 0; g < 8; g++) {
            f16x8 v;
#pragma unroll
            for (int u = 0; u < 8; u++) v[u] = row[(g * 8 + u) * 2 + bb2];
            *(f16x8*)(dst + g * 8) = v;
        }
        return;
    }

    // -------- Q/K path: unchanged proven epilogue (bias + scale + rotary) --------
    f16* __restrict__ Out = (seg == 0) ? Qb : Kb;
#pragma unroll
    for (int i = 0; i < 4; i++) {
#pragma unroll
        for (int j = 0; j < 4; j++) {
            const int n = n0 + wc * 64 + j * 16 + lr;
            const int e = n & 1023;
            const int h = e >> 6, d = e & 63;
            const float bv = bias[n];
            const float invf = invfS[e >> 1];
#pragma unroll
            for (int r = 0; r < 4; r++) {
                const int m = m0 + wr * 64 + i * 16 + lg * 4 + r;
                const int t = m >> 1, bb = m & 1;
                float val = acc[i][j][r] + bv;
                if (seg == 0) val *= 0.125f;        // Dh^-0.5
                {                                    // rotary (q and k)
                    const float vp = __shfl_xor(val, 1);
                    float sn, cn;
                    __sincosf((float)t * invf, &sn, &cn);
                    val = (e & 1) ? fmaf(vp, sn, val * cn) : fmaf(-vp, sn, val * cn);
                }
                Out[((size_t)(bb * 16 + h) * 2048 + t) * 64 + d] = (f16)val;
            }
        }
    }
}

// ---------------- Kernel 4: flash attention, TRIPLE-buffered K/V, ONE barrier/iter ----------------
__global__ __launch_bounds__(512) void attn(const f16* __restrict__ Qb,
                                            const f16* __restrict__ Kb,
                                            const f16* __restrict__ Vt,
                                            const float* __restrict__ mask,
                                            const unsigned* __restrict__ flag,
                                            f16* __restrict__ AO) {
    __shared__ __align__(16) f16 Ks[3][64 * 64];
    __shared__ __align__(16) f16 Vs[3][64 * 64];
    __shared__ __align__(16) f16 Pl[8][16][72];
    const int bh = blockIdx.x;
    const int b = bh >> 4, h = bh & 15;
    const int tid = threadIdx.x, wid = tid >> 6, lane = tid & 63;
    const int lr = lane & 15, lg = lane >> 4;
    const int l0 = blockIdx.y * 128 + wid * 16;
    const bool use_mask = (*flag) != 0;             // wave-uniform

    const int srow = tid >> 3;
    const int sc16 = (tid & 7) ^ (srow & 7);
    const f16* Kgs = Kb + ((size_t)bh * 2048 + srow) * 64 + sc16 * 8;
    const f16* Vgs = Vt + ((size_t)bh * 64 + srow) * 2048 + sc16 * 8;

    const f16* __restrict__ Qp = Qb + ((size_t)bh * 2048 + l0) * 64;
    f16x8 aq[2];
    aq[0] = *(const f16x8*)(Qp + lr * 64 + lg * 8);
    aq[1] = *(const f16x8*)(Qp + lr * 64 + 32 + lg * 8);

    float l_run[4] = {0.f, 0.f, 0.f, 0.f};
    f32x4 acc_o[4] = {};

    // prologue: tile 0 in flight
    gload16(Kgs, &Ks[0][wid * 512]);
    gload16(Vgs, &Vs[0][wid * 512]);

    int cur = 0;
    for (int t = 0; t < 32; ++t) {
        const int nxt = (cur == 2) ? 0 : cur + 1;
        if (t < 31) {                               // prefetch tile t+1 into 3rd buffer
            gload16(Kgs + (size_t)(t + 1) * 4096, &Ks[nxt][wid * 512]);
            gload16(Vgs + (size_t)(t + 1) * 64,   &Vs[nxt][wid * 512]);
            asm volatile("s_waitcnt vmcnt(2)" ::: "memory");   // tile t landed; t+1 in flight
        } else {
            asm volatile("s_waitcnt vmcnt(0)" ::: "memory");
        }
        __builtin_amdgcn_s_barrier();               // single barrier per iteration
        __builtin_amdgcn_sched_barrier(0);          // pin all following ops below the barrier

        float mk[4][4];
        if (use_mask) {
#pragma unroll
            for (int js = 0; js < 4; js++)
#pragma unroll
                for (int r = 0; r < 4; r++)
                    mk[js][r] = mask[(size_t)(l0 + lg * 4 + r) * 2048 + t * 64 + js * 16 + lr];
        }

        f32x4 sc[4] = {};
#pragma unroll
        for (int js = 0; js < 4; js++) {
            const int row = js * 16 + lr;
#pragma unroll
            for (int kk = 0; kk < 2; kk++) {
                const f16x8 bk = *(const f16x8*)&Ks[cur][row * 64 + ((kk * 4 + lg) ^ (row & 7)) * 8];
                sc[js] = mfma16(aq[kk], bk, sc[js]);
            }
        }

        if (use_mask) {
#pragma unroll
            for (int js = 0; js < 4; js++)
#pragma unroll
                for (int r = 0; r < 4; r++) {
                    const float p = __expf(sc[js][r] + mk[js][r] - 4.0f);
                    l_run[r] += p;
                    Pl[wid][lg * 4 + r][js * 16 + lr] = (f16)p;
                }
        } else {
#pragma unroll
            for (int js = 0; js < 4; js++)
#pragma unroll
                for (int r = 0; r < 4; r++) {
                    const float p = __expf(sc[js][r] - 4.0f);
                    l_run[r] += p;
                    Pl[wid][lg * 4 + r][js * 16 + lr] = (f16)p;
                }
        }

        f16x8 pa[2];
#pragma unroll
        for (int kk = 0; kk < 2; kk++) pa[kk] = *(const f16x8*)&Pl[wid][lr][kk * 32 + lg * 8];
#pragma unroll
        for (int j = 0; j < 4; j++) {
            const int row = j * 16 + lr;
#pragma unroll
            for (int kk = 0; kk < 2; kk++) {
                const f16x8 bv = *(const f16x8*)&Vs[cur][row * 64 + ((kk * 4 + lg) ^ (row & 7)) * 8];
                acc_o[j] = mfma16(pa[kk], bv, acc_o[j]);
            }
        }
        cur = nxt;                                  // no end barrier: 3-buffer rotation is safe
    }

#pragma unroll
    for (int r = 0; r < 4; r++)
#pragma unroll
        for (int off = 1; off < 16; off <<= 1) l_run[r] += __shfl_xor(l_run[r], off);

#pragma unroll
    for (int j = 0; j < 4; j++)
#pragma unroll
        for (int r = 0; r < 4; r++) {
            const float o = acc_o[j][r] / l_run[r];
            const int l = l0 + lg * 4 + r;
            AO[((size_t)l * 2 + b) * 1024 + h * 64 + j * 16 + lr] = (f16)o;
        }
}

// ---------------- Kernel 5: out projection GEMM, TRIPLE-buffered, ONE barrier/iter ----------------
__global__ __launch_bounds__(256) void oproj_gemm_v5(const f16* __restrict__ AO,
                                                     const f16* __restrict__ Wo,
                                                     const float* __restrict__ bias,
                                                     float* __restrict__ out) {
    __shared__ __align__(16) f16 As[3][64 * 64];
    __shared__ __align__(16) f16 Bs[3][128 * 64];
    const int tid = threadIdx.x;
    const int m0 = blockIdx.x * 64;
    const int n0 = blockIdx.y * 128;
    const int wid = tid >> 6, lane = tid & 63;
    const int wr = wid >> 1, wc = wid & 1;          // 2x2 waves over 64x128
    const int lr = lane & 15, lg = lane >> 4;
    const int sw = lr & 7;
    const f16* __restrict__ A = AO + (size_t)m0 * 1024;
    const f16* __restrict__ B = Wo + (size_t)n0 * 1024;

    f32x4 acc[2][4] = {};

    stage64x64(A, 1024, As[0], tid);                // 2 loads
    stage128x64(B, Bs[0], tid);                     // 4 loads

    int cur = 0;
    for (int t = 0; t < 16; ++t) {
        const int nxt = (cur == 2) ? 0 : cur + 1;
        if (t < 15) {
            stage64x64(A + (t + 1) * 64, 1024, As[nxt], tid);
            stage128x64(B + (t + 1) * 64, Bs[nxt], tid);
            asm volatile("s_waitcnt vmcnt(6)" ::: "memory");   // tile t's 6 loads done
        } else {
            asm volatile("s_waitcnt vmcnt(0)" ::: "memory");
        }
        __builtin_amdgcn_s_barrier();               // single barrier per iteration
        __builtin_amdgcn_sched_barrier(0);
#pragma unroll
        for (int kk = 0; kk < 2; kk++) {
            f16x8 a[2], b[4];
#pragma unroll
            for (int i = 0; i < 2; i++)
                a[i] = *(const f16x8*)&As[cur][(wr * 32 + i * 16 + lr) * 64 + (((kk << 2) + lg) ^ sw) * 8];
#pragma unroll
            for (int j = 0; j < 4; j++)
                b[j] = *(const f16x8*)&Bs[cur][(wc * 64 + j * 16 + lr) * 64 + (((kk << 2) + lg) ^ sw) * 8];
#pragma unroll
            for (int i = 0; i < 2; i++)
#pragma unroll
                for (int j = 0; j < 4; j++) acc[i][j] = mfma16(a[i], b[j], acc[i][j]);
        }
        cur = nxt;                                  // no end barrier: 3-buffer rotation
    }

#pragma unroll
    for (int i = 0; i < 2; i++)
#pragma unroll
        for (int j = 0; j < 4; j++) {
            const int n = n0 + wc * 64 + j * 16 + lr;
            const float bv = bias[n];
#pragma unroll
            for (int r = 0; r < 4; r++) {
                const int m = m0 + wr * 32 + i * 16 + lg * 4 + r;
                out[(size_t)m * 1024 + n] = acc[i][j][r] + bv;
            }
        }
}

extern "C" void kernel_launch(void* const* d_in, const int* in_sizes, int n_in,
                              void* d_out, int out_size, void* d_ws, size_t ws_size,
                              hipStream_t stream) {
    const float* query  = (const float*)d_in[0];
    const float* key    = (const float*)d_in[1];
    const float* value  = (const float*)d_in[2];
    const float* amask  = (const float*)d_in[5];
    const float* w_in   = (const float*)d_in[6];
    const float* b_in   = (const float*)d_in[7];
    const float* w_out  = (const float*)d_in[8];
    const float* b_out  = (const float*)d_in[9];
    float* out = (float*)d_out;

    f16* ws    = (f16*)d_ws;
    f16* Wqkv  = ws;                        // 3145728 (dead after qkv -> flag lives at byte 0)
    f16* Wo    = ws + 3145728;              // 1048576
    f16* Acts  = ws + 4194304;              // 3*4194304 (Aq|Ak|Av)
    f16* Qb    = ws + 16777216;
    f16* Kb    = ws + 20971520;
    f16* Vt    = ws + 25165824;             // V written transposed directly by qkv
    f16* AO    = ws + 8388608;              // reuse Ak (dead after qkv)
    unsigned* flag = (unsigned*)d_ws;       // in dead Wqkv region, after qkv

    prep_all<<<16384, 256, 0, stream>>>(w_in, w_out, query, key, value, ws);
    qkv_gemm_v6<<<dim3(32, 24), 256, 0, stream>>>(Acts, Wqkv, b_in, Qb, Kb, Vt);
    hipMemsetAsync(flag, 0, 4, stream);
    mask_flag<<<4096, 256, 0, stream>>>(amask, flag);
    attn<<<dim3(32, 16), 512, 0, stream>>>(Qb, Kb, Vt, amask, flag, AO);
    oproj_gemm_v5<<<dim3(64, 8), 256, 0, stream>>>(AO, Wo, b_out, out);
}